// Round 2
// 656.825 us; speedup vs baseline: 1.1011x; 1.1011x over previous
//
#include <hip/hip_runtime.h>
#include <hip/hip_bf16.h>
#include <stdint.h>

#define D 512          // D_IN == D_OUT == 512
#define D4 (D / 4)
#define SB 256         // scan blocks

typedef __bf16 bf16x8 __attribute__((ext_vector_type(8)));
typedef float  f32x4  __attribute__((ext_vector_type(4)));

__device__ __forceinline__ unsigned short f2bf(float f) {
    uint32_t u = __float_as_uint(f);
    uint32_t r = u + 0x7fffu + ((u >> 16) & 1u);   // RNE
    return (unsigned short)(r >> 16);
}

__device__ __forceinline__ uint32_t pack2(float lo, float hi) {
    return (uint32_t)f2bf(lo) | ((uint32_t)f2bf(hi) << 16);
}

// ---------------------------------------------------------------- cvt X -> bf16
__global__ __launch_bounds__(256) void cvt_x_kernel(const float4* __restrict__ x,
                                                    uint4* __restrict__ xb,
                                                    long n8) {
    long i = (long)blockIdx.x * 256 + threadIdx.x;   // one thread = 8 elements
    if (i >= n8) return;
    float4 a = x[i * 2];
    float4 b = x[i * 2 + 1];
    uint4 o;
    o.x = pack2(a.x, a.y);
    o.y = pack2(a.z, a.w);
    o.z = pack2(b.x, b.y);
    o.w = pack2(b.z, b.w);
    xb[i] = o;
}

// ------------------------------------------------- transpose + cvt W -> Wt bf16
__global__ __launch_bounds__(256) void cvt_w_kernel(const float* __restrict__ w,
                                                    unsigned short* __restrict__ wt) {
    __shared__ float t[32][33];
    const int tx = threadIdx.x & 31;
    const int ty = threadIdx.x >> 5;       // 0..7
    const int n0 = blockIdx.x * 32;
    const int k0 = blockIdx.y * 32;
#pragma unroll
    for (int i = 0; i < 4; ++i)
        t[ty + i * 8][tx] = w[(long)(k0 + ty + i * 8) * D + n0 + tx];
    __syncthreads();
#pragma unroll
    for (int i = 0; i < 4; ++i)
        wt[(long)(n0 + ty + i * 8) * D + k0 + tx] = f2bf(t[tx][ty + i * 8]);
}

// ---------------------------------------------------------------- zero int buf
__global__ __launch_bounds__(256) void zero_kernel(int* __restrict__ p, int n) {
    int i = blockIdx.x * 256 + threadIdx.x;
    if (i < n) p[i] = 0;
}

// ------------------------------------------------------------ row histogram
__global__ __launch_bounds__(256) void hist_kernel(const int* __restrict__ erow,
                                                   int* __restrict__ cnt, int nE) {
    int i = blockIdx.x * 256 + threadIdx.x;
    int stride = gridDim.x * 256;
    for (; i < nE; i += stride) atomicAdd(&cnt[erow[i]], 1);
}

// ------------------------------------------- multi-block scan, pass 1: partials
__global__ __launch_bounds__(256) void scan_part_kernel(const int* __restrict__ cnt,
                                                        int* __restrict__ bsum, int M) {
    const int b = blockIdx.x;
    const int chunk = (M + SB - 1) / SB;
    const int lo = b * chunk;
    const int hi = min(M, lo + chunk);
    int s = 0;
    for (int i = lo + (int)threadIdx.x; i < hi; i += 256) s += cnt[i];
#pragma unroll
    for (int off = 32; off; off >>= 1) s += __shfl_down(s, off);
    __shared__ int ws[4];
    const int wv = threadIdx.x >> 6;
    if ((threadIdx.x & 63) == 0) ws[wv] = s;
    __syncthreads();
    if (threadIdx.x == 0) bsum[b] = ws[0] + ws[1] + ws[2] + ws[3];
}

// ------------------------------- pass 2: single-block scan of SB block sums
__global__ __launch_bounds__(SB) void scan_base_kernel(const int* __restrict__ bsum,
                                                       int* __restrict__ bbase,
                                                       int* __restrict__ rowptr, int M) {
    const int tid  = (int)threadIdx.x;
    const int lane = tid & 63;
    const int wv   = tid >> 6;
    const int v = bsum[tid];
    int s = v;
#pragma unroll
    for (int off = 1; off < 64; off <<= 1) {
        int t = __shfl_up(s, off);
        if (lane >= off) s += t;
    }
    __shared__ int wsum[4];
    if (lane == 63) wsum[wv] = s;
    __syncthreads();
    int wb = 0;
    for (int j = 0; j < wv; ++j) wb += wsum[j];
    bbase[tid] = wb + s - v;
    if (tid == SB - 1) rowptr[M] = wb + s;   // total edge count
}

// --------------- pass 3: per-chunk exclusive scan + carry; heads MAY alias cnt
__global__ __launch_bounds__(256) void scan_final_kernel(const int* __restrict__ cnt,
                                                         const int* __restrict__ bbase,
                                                         int* __restrict__ rowptr,
                                                         int* __restrict__ heads, int M) {
    const int b = blockIdx.x;
    const int chunk = (M + SB - 1) / SB;
    const int lo = b * chunk;
    const int hi = min(M, lo + chunk);
    const int lane = threadIdx.x & 63;
    const int wv   = threadIdx.x >> 6;
    __shared__ int wsum[4];
    __shared__ int s_carry;
    if (threadIdx.x == 0) s_carry = bbase[b];
    __syncthreads();
    for (int base = lo; base < hi; base += 256) {
        const int i = base + (int)threadIdx.x;
        const int v = (i < hi) ? cnt[i] : 0;
        int s = v;
#pragma unroll
        for (int off = 1; off < 64; off <<= 1) {
            int t = __shfl_up(s, off);
            if (lane >= off) s += t;
        }
        if (lane == 63) wsum[wv] = s;
        __syncthreads();
        int wb = s_carry;
        for (int j = 0; j < wv; ++j) wb += wsum[j];
        const int excl = wb + s - v;
        if (i < hi) { rowptr[i] = excl; heads[i] = excl; }
        __syncthreads();
        if (threadIdx.x == 0) s_carry += wsum[0] + wsum[1] + wsum[2] + wsum[3];
        __syncthreads();
    }
}

// --------------------------------------- counting-sort edges by dest row
__global__ __launch_bounds__(256) void edge_sort_kernel(const int* __restrict__ erow,
                                                        const int* __restrict__ ecol,
                                                        const float* __restrict__ eval,
                                                        int* __restrict__ heads,
                                                        int* __restrict__ scol,
                                                        float* __restrict__ sval,
                                                        int nE) {
    int i = blockIdx.x * 256 + threadIdx.x;
    int stride = gridDim.x * 256;
    for (; i < nE; i += stride) {
        const int r = erow[i];
        const int p = atomicAdd(&heads[r], 1);
        scol[p] = ecol[i];
        sval[p] = eval[i];
    }
}

// --------------------------------------------------------- GEMM: Sup = Xb * W
// 128x128 tile, BK=64, 256 threads (4 waves, 2x2), 16x16x32 bf16 MFMA.
__global__ __launch_bounds__(256) void gemm_kernel(const unsigned short* __restrict__ Xb,
                                                   const unsigned short* __restrict__ Wt,
                                                   unsigned short* __restrict__ Sup,
                                                   int M) {
    __shared__ __align__(16) unsigned short As[128 * 64];
    __shared__ __align__(16) unsigned short Bs[128 * 64];
    const int tid  = threadIdx.x;
    const int wv   = tid >> 6;
    const int lane = tid & 63;
    const int tileM = blockIdx.x * 128;
    const int tileN = blockIdx.y * 128;
    const int wm = wv >> 1, wn = wv & 1;

    f32x4 acc[4][4];
#pragma unroll
    for (int i = 0; i < 4; ++i)
#pragma unroll
        for (int j = 0; j < 4; ++j) acc[i][j] = (f32x4)0.0f;

    const int srow = lane >> 3;               // row within chunk
    const int sgrn = (lane & 7) ^ srow;       // swizzled source granule
    const int scol = sgrn * 8;

    const int fm  = lane & 15;
    const int fkq = lane >> 4;                // 0..3

    for (int kt = 0; kt < D; kt += 64) {
        __syncthreads();
#pragma unroll
        for (int i = 0; i < 4; ++i) {
            const int c   = wv * 4 + i;
            const int row = c * 8 + srow;
            int rg = tileM + row;
            rg = (rg < M) ? rg : (M - 1);
            const unsigned short* ga = Xb + (long)rg * D + kt + scol;
            __builtin_amdgcn_global_load_lds(
                (const __attribute__((address_space(1))) void*)ga,
                (__attribute__((address_space(3))) void*)(As + c * 512), 16, 0, 0);
            const unsigned short* gb = Wt + (long)(tileN + row) * D + kt + scol;
            __builtin_amdgcn_global_load_lds(
                (const __attribute__((address_space(1))) void*)gb,
                (__attribute__((address_space(3))) void*)(Bs + c * 512), 16, 0, 0);
        }
        __syncthreads();
#pragma unroll
        for (int kk = 0; kk < 2; ++kk) {
            bf16x8 af[4], bfr[4];
#pragma unroll
            for (int mi = 0; mi < 4; ++mi) {
                const int m = wm * 64 + mi * 16 + fm;
                const int g = (kk * 4 + fkq) ^ (m & 7);
                af[mi] = *(const bf16x8*)(As + m * 64 + g * 8);
            }
#pragma unroll
            for (int ni = 0; ni < 4; ++ni) {
                const int n = wn * 64 + ni * 16 + fm;
                const int g = (kk * 4 + fkq) ^ (n & 7);
                bfr[ni] = *(const bf16x8*)(Bs + n * 64 + g * 8);
            }
#pragma unroll
            for (int mi = 0; mi < 4; ++mi)
#pragma unroll
                for (int ni = 0; ni < 4; ++ni)
                    acc[mi][ni] = __builtin_amdgcn_mfma_f32_16x16x32_bf16(
                        af[mi], bfr[ni], acc[mi][ni], 0, 0, 0);
        }
    }

    const int colb = tileN + wn * 64 + fm;
#pragma unroll
    for (int mi = 0; mi < 4; ++mi) {
        const int rb = tileM + wm * 64 + mi * 16 + fkq * 4;
#pragma unroll
        for (int r = 0; r < 4; ++r) {
            const int row = rb + r;
            if (row < M) {
                unsigned short* dst = Sup + (long)row * D + colb;
#pragma unroll
                for (int ni = 0; ni < 4; ++ni)
                    dst[ni * 16] = f2bf(acc[mi][ni][r]);
            }
        }
    }
}

// ----------------------------- pull aggregation: out[r] = b + sum val*Sup[col]
// one wave per row; lane covers 8 columns; 4-edge software pipeline for MLP;
// nontemporal out stores keep Sup resident in L3.
__global__ __launch_bounds__(256) void aggregate_kernel(const unsigned short* __restrict__ sup,
                                                        const int* __restrict__ rowptr,
                                                        const int* __restrict__ scol,
                                                        const float* __restrict__ sval,
                                                        const float* __restrict__ bias,
                                                        float* __restrict__ out,
                                                        int M) {
    const int lane = threadIdx.x & 63;
    const int row  = (int)((blockIdx.x * 256 + threadIdx.x) >> 6);
    if (row >= M) return;
    int e = rowptr[row];
    const int end = rowptr[row + 1];

    const float4 b0 = ((const float4*)bias)[lane * 2];
    const float4 b1 = ((const float4*)bias)[lane * 2 + 1];
    float acc[8] = {b0.x, b0.y, b0.z, b0.w, b1.x, b1.y, b1.z, b1.w};

    // 4-deep pipelined main loop: 4 independent gathers in flight per wave
    for (; e + 4 <= end; e += 4) {
        const int c0 = scol[e + 0], c1 = scol[e + 1];
        const int c2 = scol[e + 2], c3 = scol[e + 3];
        const float v0 = sval[e + 0], v1 = sval[e + 1];
        const float v2 = sval[e + 2], v3 = sval[e + 3];
        const uint4 p0 = *(const uint4*)(sup + (long)c0 * D + lane * 8);
        const uint4 p1 = *(const uint4*)(sup + (long)c1 * D + lane * 8);
        const uint4 p2 = *(const uint4*)(sup + (long)c2 * D + lane * 8);
        const uint4 p3 = *(const uint4*)(sup + (long)c3 * D + lane * 8);
        const uint32_t pk0[4] = {p0.x, p0.y, p0.z, p0.w};
        const uint32_t pk1[4] = {p1.x, p1.y, p1.z, p1.w};
        const uint32_t pk2[4] = {p2.x, p2.y, p2.z, p2.w};
        const uint32_t pk3[4] = {p3.x, p3.y, p3.z, p3.w};
#pragma unroll
        for (int i = 0; i < 4; ++i) {
            acc[i * 2]     += v0 * __uint_as_float((pk0[i] & 0x0000ffffu) << 16);
            acc[i * 2 + 1] += v0 * __uint_as_float(pk0[i] & 0xffff0000u);
            acc[i * 2]     += v1 * __uint_as_float((pk1[i] & 0x0000ffffu) << 16);
            acc[i * 2 + 1] += v1 * __uint_as_float(pk1[i] & 0xffff0000u);
            acc[i * 2]     += v2 * __uint_as_float((pk2[i] & 0x0000ffffu) << 16);
            acc[i * 2 + 1] += v2 * __uint_as_float(pk2[i] & 0xffff0000u);
            acc[i * 2]     += v3 * __uint_as_float((pk3[i] & 0x0000ffffu) << 16);
            acc[i * 2 + 1] += v3 * __uint_as_float(pk3[i] & 0xffff0000u);
        }
    }
    // 2-deep tail
    for (; e + 2 <= end; e += 2) {
        const int c0 = scol[e + 0], c1 = scol[e + 1];
        const float v0 = sval[e + 0], v1 = sval[e + 1];
        const uint4 p0 = *(const uint4*)(sup + (long)c0 * D + lane * 8);
        const uint4 p1 = *(const uint4*)(sup + (long)c1 * D + lane * 8);
        const uint32_t pk0[4] = {p0.x, p0.y, p0.z, p0.w};
        const uint32_t pk1[4] = {p1.x, p1.y, p1.z, p1.w};
#pragma unroll
        for (int i = 0; i < 4; ++i) {
            acc[i * 2]     += v0 * __uint_as_float((pk0[i] & 0x0000ffffu) << 16);
            acc[i * 2 + 1] += v0 * __uint_as_float(pk0[i] & 0xffff0000u);
            acc[i * 2]     += v1 * __uint_as_float((pk1[i] & 0x0000ffffu) << 16);
            acc[i * 2 + 1] += v1 * __uint_as_float(pk1[i] & 0xffff0000u);
        }
    }
    // scalar tail
    for (; e < end; ++e) {
        const int c   = scol[e];
        const float v = sval[e];
        const uint4 p = *(const uint4*)(sup + (long)c * D + lane * 8);
        const uint32_t pk[4] = {p.x, p.y, p.z, p.w};
#pragma unroll
        for (int i = 0; i < 4; ++i) {
            acc[i * 2]     += v * __uint_as_float((pk[i] & 0x0000ffffu) << 16);
            acc[i * 2 + 1] += v * __uint_as_float(pk[i] & 0xffff0000u);
        }
    }

    f32x4* dst = (f32x4*)(out + (long)row * D);
    f32x4 o0 = {acc[0], acc[1], acc[2], acc[3]};
    f32x4 o1 = {acc[4], acc[5], acc[6], acc[7]};
    __builtin_nontemporal_store(o0, dst + lane * 2);
    __builtin_nontemporal_store(o1, dst + lane * 2 + 1);
}

extern "C" void kernel_launch(void* const* d_in, const int* in_sizes, int n_in,
                              void* d_out, int out_size, void* d_ws, size_t ws_size,
                              hipStream_t stream) {
    const float* x        = (const float*)d_in[0];
    const int*   adj_row  = (const int*)d_in[1];
    const int*   adj_col  = (const int*)d_in[2];
    const float* adj_vals = (const float*)d_in[3];
    const float* weight   = (const float*)d_in[4];
    const float* bias     = (const float*)d_in[5];
    float* out = (float*)d_out;

    const int M = in_sizes[0] / D;     // 100000 nodes
    const int E = in_sizes[1];         // 800000 edges

    // workspace layout (~213 MB)
    char* ws = (char*)d_ws;
    size_t off = 0;
    unsigned short* Xb  = (unsigned short*)(ws + off); off += (size_t)M * D * 2;
    unsigned short* Sup = (unsigned short*)(ws + off); off += (size_t)M * D * 2;
    unsigned short* Wt  = (unsigned short*)(ws + off); off += (size_t)D * D * 2;
    int*   rowptr = (int*)(ws + off);   off += (size_t)(M + 1) * 4;
    int*   heads  = (int*)(ws + off);   off += (size_t)M * 4;        // also the histogram
    int*   scol   = (int*)(ws + off);   off += (size_t)E * 4;
    float* sval   = (float*)(ws + off); off += (size_t)E * 4;
    int*   bsum   = (int*)(ws + off);   off += (size_t)SB * 4;
    int*   bbase  = (int*)(ws + off);   off += (size_t)SB * 4;
    int* cnt = heads;                   // histogram aliases heads

    // --- CSR construction (independent of GEMM chain) ---
    zero_kernel<<<(M + 255) / 256, 256, 0, stream>>>(cnt, M);
    hist_kernel<<<1024, 256, 0, stream>>>(adj_row, cnt, E);
    scan_part_kernel<<<SB, 256, 0, stream>>>(cnt, bsum, M);
    scan_base_kernel<<<1, SB, 0, stream>>>(bsum, bbase, rowptr, M);
    scan_final_kernel<<<SB, 256, 0, stream>>>(cnt, bbase, rowptr, heads, M);
    edge_sort_kernel<<<1024, 256, 0, stream>>>(adj_row, adj_col, adj_vals,
                                               heads, scol, sval, E);

    // --- dense chain ---
    {
        long n8 = (long)M * D / 8;
        cvt_x_kernel<<<(int)((n8 + 255) / 256), 256, 0, stream>>>(
            (const float4*)x, (uint4*)Xb, n8);
    }
    cvt_w_kernel<<<dim3(D / 32, D / 32), 256, 0, stream>>>(weight, Wt);
    gemm_kernel<<<dim3((M + 127) / 128, D / 128), 256, 0, stream>>>(Xb, Wt, Sup, M);

    // --- pull aggregation (no atomics) ---
    aggregate_kernel<<<(M * 64 + 255) / 256, 256, 0, stream>>>(
        Sup, rowptr, scol, sval, bias, out, M);
}

// Round 3
// 649.020 us; speedup vs baseline: 1.1143x; 1.0120x over previous
//
#include <hip/hip_runtime.h>
#include <hip/hip_bf16.h>
#include <stdint.h>

#define D 512          // D_IN == D_OUT == 512
#define D4 (D / 4)
#define SB 256         // scan blocks
#define CHUNK 256      // aggregation column chunk (2 passes)

typedef __bf16 bf16x8 __attribute__((ext_vector_type(8)));
typedef float  f32x4  __attribute__((ext_vector_type(4)));

__device__ __forceinline__ unsigned short f2bf(float f) {
    uint32_t u = __float_as_uint(f);
    uint32_t r = u + 0x7fffu + ((u >> 16) & 1u);   // RNE
    return (unsigned short)(r >> 16);
}

__device__ __forceinline__ uint32_t pack2(float lo, float hi) {
    return (uint32_t)f2bf(lo) | ((uint32_t)f2bf(hi) << 16);
}

__device__ __forceinline__ float bflo(uint32_t p) {
    return __uint_as_float((p & 0x0000ffffu) << 16);
}
__device__ __forceinline__ float bfhi(uint32_t p) {
    return __uint_as_float(p & 0xffff0000u);
}

// ---------------------------------------------------------------- cvt X -> bf16
__global__ __launch_bounds__(256) void cvt_x_kernel(const float4* __restrict__ x,
                                                    uint4* __restrict__ xb,
                                                    long n8) {
    long i = (long)blockIdx.x * 256 + threadIdx.x;   // one thread = 8 elements
    if (i >= n8) return;
    float4 a = x[i * 2];
    float4 b = x[i * 2 + 1];
    uint4 o;
    o.x = pack2(a.x, a.y);
    o.y = pack2(a.z, a.w);
    o.z = pack2(b.x, b.y);
    o.w = pack2(b.z, b.w);
    xb[i] = o;
}

// ------------------------------------------------- transpose + cvt W -> Wt bf16
__global__ __launch_bounds__(256) void cvt_w_kernel(const float* __restrict__ w,
                                                    unsigned short* __restrict__ wt) {
    __shared__ float t[32][33];
    const int tx = threadIdx.x & 31;
    const int ty = threadIdx.x >> 5;       // 0..7
    const int n0 = blockIdx.x * 32;
    const int k0 = blockIdx.y * 32;
#pragma unroll
    for (int i = 0; i < 4; ++i)
        t[ty + i * 8][tx] = w[(long)(k0 + ty + i * 8) * D + n0 + tx];
    __syncthreads();
#pragma unroll
    for (int i = 0; i < 4; ++i)
        wt[(long)(n0 + ty + i * 8) * D + k0 + tx] = f2bf(t[tx][ty + i * 8]);
}

// ---------------------------------------------------------------- zero int buf
__global__ __launch_bounds__(256) void zero_kernel(int* __restrict__ p, int n) {
    int i = blockIdx.x * 256 + threadIdx.x;
    if (i < n) p[i] = 0;
}

// ------------------------------------------------------------ row histogram
__global__ __launch_bounds__(256) void hist_kernel(const int* __restrict__ erow,
                                                   int* __restrict__ cnt, int nE) {
    int i = blockIdx.x * 256 + threadIdx.x;
    int stride = gridDim.x * 256;
    for (; i < nE; i += stride) atomicAdd(&cnt[erow[i]], 1);
}

// ------------------------------------------- multi-block scan, pass 1: partials
__global__ __launch_bounds__(256) void scan_part_kernel(const int* __restrict__ cnt,
                                                        int* __restrict__ bsum, int M) {
    const int b = blockIdx.x;
    const int chunk = (M + SB - 1) / SB;
    const int lo = b * chunk;
    const int hi = min(M, lo + chunk);
    int s = 0;
    for (int i = lo + (int)threadIdx.x; i < hi; i += 256) s += cnt[i];
#pragma unroll
    for (int off = 32; off; off >>= 1) s += __shfl_down(s, off);
    __shared__ int ws[4];
    const int wv = threadIdx.x >> 6;
    if ((threadIdx.x & 63) == 0) ws[wv] = s;
    __syncthreads();
    if (threadIdx.x == 0) bsum[b] = ws[0] + ws[1] + ws[2] + ws[3];
}

// ------------------------------- pass 2: single-block scan of SB block sums
__global__ __launch_bounds__(SB) void scan_base_kernel(const int* __restrict__ bsum,
                                                       int* __restrict__ bbase,
                                                       int* __restrict__ rowptr, int M) {
    const int tid  = (int)threadIdx.x;
    const int lane = tid & 63;
    const int wv   = tid >> 6;
    const int v = bsum[tid];
    int s = v;
#pragma unroll
    for (int off = 1; off < 64; off <<= 1) {
        int t = __shfl_up(s, off);
        if (lane >= off) s += t;
    }
    __shared__ int wsum[4];
    if (lane == 63) wsum[wv] = s;
    __syncthreads();
    int wb = 0;
    for (int j = 0; j < wv; ++j) wb += wsum[j];
    bbase[tid] = wb + s - v;
    if (tid == SB - 1) rowptr[M] = wb + s;   // total edge count
}

// --------------- pass 3: per-chunk exclusive scan + carry; heads MAY alias cnt
__global__ __launch_bounds__(256) void scan_final_kernel(const int* __restrict__ cnt,
                                                         const int* __restrict__ bbase,
                                                         int* __restrict__ rowptr,
                                                         int* __restrict__ heads, int M) {
    const int b = blockIdx.x;
    const int chunk = (M + SB - 1) / SB;
    const int lo = b * chunk;
    const int hi = min(M, lo + chunk);
    const int lane = threadIdx.x & 63;
    const int wv   = threadIdx.x >> 6;
    __shared__ int wsum[4];
    __shared__ int s_carry;
    if (threadIdx.x == 0) s_carry = bbase[b];
    __syncthreads();
    for (int base = lo; base < hi; base += 256) {
        const int i = base + (int)threadIdx.x;
        const int v = (i < hi) ? cnt[i] : 0;
        int s = v;
#pragma unroll
        for (int off = 1; off < 64; off <<= 1) {
            int t = __shfl_up(s, off);
            if (lane >= off) s += t;
        }
        if (lane == 63) wsum[wv] = s;
        __syncthreads();
        int wb = s_carry;
        for (int j = 0; j < wv; ++j) wb += wsum[j];
        const int excl = wb + s - v;
        if (i < hi) { rowptr[i] = excl; heads[i] = excl; }
        __syncthreads();
        if (threadIdx.x == 0) s_carry += wsum[0] + wsum[1] + wsum[2] + wsum[3];
        __syncthreads();
    }
}

// --------------------------------------- counting-sort edges by dest row
__global__ __launch_bounds__(256) void edge_sort_kernel(const int* __restrict__ erow,
                                                        const int* __restrict__ ecol,
                                                        const float* __restrict__ eval,
                                                        int* __restrict__ heads,
                                                        int* __restrict__ scol,
                                                        float* __restrict__ sval,
                                                        int nE) {
    int i = blockIdx.x * 256 + threadIdx.x;
    int stride = gridDim.x * 256;
    for (; i < nE; i += stride) {
        const int r = erow[i];
        const int p = atomicAdd(&heads[r], 1);
        scol[p] = ecol[i];
        sval[p] = eval[i];
    }
}

// --------------------------------------------------------- GEMM: Sup = Xb * W
// 128x128 tile, BK=64, 256 threads (4 waves, 2x2), 16x16x32 bf16 MFMA.
__global__ __launch_bounds__(256) void gemm_kernel(const unsigned short* __restrict__ Xb,
                                                   const unsigned short* __restrict__ Wt,
                                                   unsigned short* __restrict__ Sup,
                                                   int M) {
    __shared__ __align__(16) unsigned short As[128 * 64];
    __shared__ __align__(16) unsigned short Bs[128 * 64];
    const int tid  = threadIdx.x;
    const int wv   = tid >> 6;
    const int lane = tid & 63;
    const int tileM = blockIdx.x * 128;
    const int tileN = blockIdx.y * 128;
    const int wm = wv >> 1, wn = wv & 1;

    f32x4 acc[4][4];
#pragma unroll
    for (int i = 0; i < 4; ++i)
#pragma unroll
        for (int j = 0; j < 4; ++j) acc[i][j] = (f32x4)0.0f;

    const int srow = lane >> 3;               // row within chunk
    const int sgrn = (lane & 7) ^ srow;       // swizzled source granule
    const int scol = sgrn * 8;

    const int fm  = lane & 15;
    const int fkq = lane >> 4;                // 0..3

    for (int kt = 0; kt < D; kt += 64) {
        __syncthreads();
#pragma unroll
        for (int i = 0; i < 4; ++i) {
            const int c   = wv * 4 + i;
            const int row = c * 8 + srow;
            int rg = tileM + row;
            rg = (rg < M) ? rg : (M - 1);
            const unsigned short* ga = Xb + (long)rg * D + kt + scol;
            __builtin_amdgcn_global_load_lds(
                (const __attribute__((address_space(1))) void*)ga,
                (__attribute__((address_space(3))) void*)(As + c * 512), 16, 0, 0);
            const unsigned short* gb = Wt + (long)(tileN + row) * D + kt + scol;
            __builtin_amdgcn_global_load_lds(
                (const __attribute__((address_space(1))) void*)gb,
                (__attribute__((address_space(3))) void*)(Bs + c * 512), 16, 0, 0);
        }
        __syncthreads();
#pragma unroll
        for (int kk = 0; kk < 2; ++kk) {
            bf16x8 af[4], bfr[4];
#pragma unroll
            for (int mi = 0; mi < 4; ++mi) {
                const int m = wm * 64 + mi * 16 + fm;
                const int g = (kk * 4 + fkq) ^ (m & 7);
                af[mi] = *(const bf16x8*)(As + m * 64 + g * 8);
            }
#pragma unroll
            for (int ni = 0; ni < 4; ++ni) {
                const int n = wn * 64 + ni * 16 + fm;
                const int g = (kk * 4 + fkq) ^ (n & 7);
                bfr[ni] = *(const bf16x8*)(Bs + n * 64 + g * 8);
            }
#pragma unroll
            for (int mi = 0; mi < 4; ++mi)
#pragma unroll
                for (int ni = 0; ni < 4; ++ni)
                    acc[mi][ni] = __builtin_amdgcn_mfma_f32_16x16x32_bf16(
                        af[mi], bfr[ni], acc[mi][ni], 0, 0, 0);
        }
    }

    const int colb = tileN + wn * 64 + fm;
#pragma unroll
    for (int mi = 0; mi < 4; ++mi) {
        const int rb = tileM + wm * 64 + mi * 16 + fkq * 4;
#pragma unroll
        for (int r = 0; r < 4; ++r) {
            const int row = rb + r;
            if (row < M) {
                unsigned short* dst = Sup + (long)row * D + colb;
#pragma unroll
                for (int ni = 0; ni < 4; ++ni)
                    dst[ni * 16] = f2bf(acc[mi][ni][r]);
            }
        }
    }
}

// ----------------------------- pull aggregation, column-chunked:
// out[r][c0:c0+CHUNK] = b[c0:...] + sum val*Sup[col][c0:...]
// One wave per row; lane covers 4 cols (8B gathers). Two sequential launches
// (c0 = 0, 256) shrink the random-gather hot set to 51 MB so it stays
// L3-resident against the streaming out writes.
__global__ __launch_bounds__(256) void aggregate_kernel(const unsigned short* __restrict__ sup,
                                                        const int* __restrict__ rowptr,
                                                        const int* __restrict__ scol,
                                                        const float* __restrict__ sval,
                                                        const float* __restrict__ bias,
                                                        float* __restrict__ out,
                                                        int M, int c0) {
    const int lane = threadIdx.x & 63;
    const int row  = (int)((blockIdx.x * 256 + threadIdx.x) >> 6);
    if (row >= M) return;
    int e = rowptr[row];
    const int end = rowptr[row + 1];

    const float4 b0 = *(const float4*)(bias + c0 + lane * 4);
    float acc[4] = {b0.x, b0.y, b0.z, b0.w};

    const unsigned short* supc = sup + c0 + lane * 4;   // per-lane column base

    // 4-deep pipelined main loop: 4 independent 8B gathers in flight per lane
    for (; e + 4 <= end; e += 4) {
        const int cc0 = scol[e + 0], cc1 = scol[e + 1];
        const int cc2 = scol[e + 2], cc3 = scol[e + 3];
        const float v0 = sval[e + 0], v1 = sval[e + 1];
        const float v2 = sval[e + 2], v3 = sval[e + 3];
        const uint2 p0 = *(const uint2*)(supc + (long)cc0 * D);
        const uint2 p1 = *(const uint2*)(supc + (long)cc1 * D);
        const uint2 p2 = *(const uint2*)(supc + (long)cc2 * D);
        const uint2 p3 = *(const uint2*)(supc + (long)cc3 * D);
        acc[0] += v0 * bflo(p0.x); acc[1] += v0 * bfhi(p0.x);
        acc[2] += v0 * bflo(p0.y); acc[3] += v0 * bfhi(p0.y);
        acc[0] += v1 * bflo(p1.x); acc[1] += v1 * bfhi(p1.x);
        acc[2] += v1 * bflo(p1.y); acc[3] += v1 * bfhi(p1.y);
        acc[0] += v2 * bflo(p2.x); acc[1] += v2 * bfhi(p2.x);
        acc[2] += v2 * bflo(p2.y); acc[3] += v2 * bfhi(p2.y);
        acc[0] += v3 * bflo(p3.x); acc[1] += v3 * bfhi(p3.x);
        acc[2] += v3 * bflo(p3.y); acc[3] += v3 * bfhi(p3.y);
    }
    for (; e + 2 <= end; e += 2) {
        const int cc0 = scol[e + 0], cc1 = scol[e + 1];
        const float v0 = sval[e + 0], v1 = sval[e + 1];
        const uint2 p0 = *(const uint2*)(supc + (long)cc0 * D);
        const uint2 p1 = *(const uint2*)(supc + (long)cc1 * D);
        acc[0] += v0 * bflo(p0.x); acc[1] += v0 * bfhi(p0.x);
        acc[2] += v0 * bflo(p0.y); acc[3] += v0 * bfhi(p0.y);
        acc[0] += v1 * bflo(p1.x); acc[1] += v1 * bfhi(p1.x);
        acc[2] += v1 * bflo(p1.y); acc[3] += v1 * bfhi(p1.y);
    }
    for (; e < end; ++e) {
        const int cc = scol[e];
        const float v = sval[e];
        const uint2 p = *(const uint2*)(supc + (long)cc * D);
        acc[0] += v * bflo(p.x); acc[1] += v * bfhi(p.x);
        acc[2] += v * bflo(p.y); acc[3] += v * bfhi(p.y);
    }

    *(float4*)(out + (long)row * D + c0 + lane * 4) =
        (float4){acc[0], acc[1], acc[2], acc[3]};
}

extern "C" void kernel_launch(void* const* d_in, const int* in_sizes, int n_in,
                              void* d_out, int out_size, void* d_ws, size_t ws_size,
                              hipStream_t stream) {
    const float* x        = (const float*)d_in[0];
    const int*   adj_row  = (const int*)d_in[1];
    const int*   adj_col  = (const int*)d_in[2];
    const float* adj_vals = (const float*)d_in[3];
    const float* weight   = (const float*)d_in[4];
    const float* bias     = (const float*)d_in[5];
    float* out = (float*)d_out;

    const int M = in_sizes[0] / D;     // 100000 nodes
    const int E = in_sizes[1];         // 800000 edges

    // workspace layout (~213 MB)
    char* ws = (char*)d_ws;
    size_t off = 0;
    unsigned short* Xb  = (unsigned short*)(ws + off); off += (size_t)M * D * 2;
    unsigned short* Sup = (unsigned short*)(ws + off); off += (size_t)M * D * 2;
    unsigned short* Wt  = (unsigned short*)(ws + off); off += (size_t)D * D * 2;
    int*   rowptr = (int*)(ws + off);   off += (size_t)(M + 1) * 4;
    int*   heads  = (int*)(ws + off);   off += (size_t)M * 4;        // also the histogram
    int*   scol   = (int*)(ws + off);   off += (size_t)E * 4;
    float* sval   = (float*)(ws + off); off += (size_t)E * 4;
    int*   bsum   = (int*)(ws + off);   off += (size_t)SB * 4;
    int*   bbase  = (int*)(ws + off);   off += (size_t)SB * 4;
    int* cnt = heads;                   // histogram aliases heads

    // --- CSR construction (independent of GEMM chain) ---
    zero_kernel<<<(M + 255) / 256, 256, 0, stream>>>(cnt, M);
    hist_kernel<<<1024, 256, 0, stream>>>(adj_row, cnt, E);
    scan_part_kernel<<<SB, 256, 0, stream>>>(cnt, bsum, M);
    scan_base_kernel<<<1, SB, 0, stream>>>(bsum, bbase, rowptr, M);
    scan_final_kernel<<<SB, 256, 0, stream>>>(cnt, bbase, rowptr, heads, M);
    edge_sort_kernel<<<1024, 256, 0, stream>>>(adj_row, adj_col, adj_vals,
                                               heads, scol, sval, E);

    // --- dense chain ---
    {
        long n8 = (long)M * D / 8;
        cvt_x_kernel<<<(int)((n8 + 255) / 256), 256, 0, stream>>>(
            (const float4*)x, (uint4*)Xb, n8);
    }
    cvt_w_kernel<<<dim3(D / 32, D / 32), 256, 0, stream>>>(weight, Wt);
    gemm_kernel<<<dim3((M + 127) / 128, D / 128), 256, 0, stream>>>(Xb, Wt, Sup, M);

    // --- pull aggregation, 2 temporally-separated column passes ---
    aggregate_kernel<<<(M * 64 + 255) / 256, 256, 0, stream>>>(
        Sup, rowptr, scol, sval, bias, out, M, 0);
    aggregate_kernel<<<(M * 64 + 255) / 256, 256, 0, stream>>>(
        Sup, rowptr, scol, sval, bias, out, M, CHUNK);
}

// Round 4
// 609.422 us; speedup vs baseline: 1.1867x; 1.0650x over previous
//
#include <hip/hip_runtime.h>
#include <hip/hip_bf16.h>
#include <stdint.h>

#define D 512          // D_IN == D_OUT == 512
#define SB 256         // scan blocks
#define CHUNK 256      // aggregation column chunk (2 passes)
#define BM 64          // gemm row tile

typedef __bf16 bf16x8 __attribute__((ext_vector_type(8)));
typedef float  f32x4  __attribute__((ext_vector_type(4)));

__device__ __forceinline__ unsigned short f2bf(float f) {
    uint32_t u = __float_as_uint(f);
    uint32_t r = u + 0x7fffu + ((u >> 16) & 1u);   // RNE
    return (unsigned short)(r >> 16);
}

__device__ __forceinline__ uint32_t pack2(float lo, float hi) {
    return (uint32_t)f2bf(lo) | ((uint32_t)f2bf(hi) << 16);
}

__device__ __forceinline__ float bflo(uint32_t p) {
    return __uint_as_float((p & 0x0000ffffu) << 16);
}
__device__ __forceinline__ float bfhi(uint32_t p) {
    return __uint_as_float(p & 0xffff0000u);
}

// ------------------------------------------------- transpose + cvt W -> Wt bf16
__global__ __launch_bounds__(256) void cvt_w_kernel(const float* __restrict__ w,
                                                    unsigned short* __restrict__ wt) {
    __shared__ float t[32][33];
    const int tx = threadIdx.x & 31;
    const int ty = threadIdx.x >> 5;       // 0..7
    const int n0 = blockIdx.x * 32;
    const int k0 = blockIdx.y * 32;
#pragma unroll
    for (int i = 0; i < 4; ++i)
        t[ty + i * 8][tx] = w[(long)(k0 + ty + i * 8) * D + n0 + tx];
    __syncthreads();
#pragma unroll
    for (int i = 0; i < 4; ++i)
        wt[(long)(n0 + ty + i * 8) * D + k0 + tx] = f2bf(t[tx][ty + i * 8]);
}

// ---------------------------------------------------------------- zero int buf
__global__ __launch_bounds__(256) void zero_kernel(int* __restrict__ p, int n) {
    int i = blockIdx.x * 256 + threadIdx.x;
    if (i < n) p[i] = 0;
}

// ------------------------------------------------------------ row histogram
__global__ __launch_bounds__(256) void hist_kernel(const int* __restrict__ erow,
                                                   int* __restrict__ cnt, int nE) {
    int i = blockIdx.x * 256 + threadIdx.x;
    int stride = gridDim.x * 256;
    for (; i < nE; i += stride) atomicAdd(&cnt[erow[i]], 1);
}

// ------------------------------------------- multi-block scan, pass 1: partials
__global__ __launch_bounds__(256) void scan_part_kernel(const int* __restrict__ cnt,
                                                        int* __restrict__ bsum, int M) {
    const int b = blockIdx.x;
    const int chunk = (M + SB - 1) / SB;
    const int lo = b * chunk;
    const int hi = min(M, lo + chunk);
    int s = 0;
    for (int i = lo + (int)threadIdx.x; i < hi; i += 256) s += cnt[i];
#pragma unroll
    for (int off = 32; off; off >>= 1) s += __shfl_down(s, off);
    __shared__ int ws[4];
    const int wv = threadIdx.x >> 6;
    if ((threadIdx.x & 63) == 0) ws[wv] = s;
    __syncthreads();
    if (threadIdx.x == 0) bsum[b] = ws[0] + ws[1] + ws[2] + ws[3];
}

// ------------------------------- pass 2: single-block scan of SB block sums
__global__ __launch_bounds__(SB) void scan_base_kernel(const int* __restrict__ bsum,
                                                       int* __restrict__ bbase,
                                                       int* __restrict__ rowptr, int M) {
    const int tid  = (int)threadIdx.x;
    const int lane = tid & 63;
    const int wv   = tid >> 6;
    const int v = bsum[tid];
    int s = v;
#pragma unroll
    for (int off = 1; off < 64; off <<= 1) {
        int t = __shfl_up(s, off);
        if (lane >= off) s += t;
    }
    __shared__ int wsum[4];
    if (lane == 63) wsum[wv] = s;
    __syncthreads();
    int wb = 0;
    for (int j = 0; j < wv; ++j) wb += wsum[j];
    bbase[tid] = wb + s - v;
    if (tid == SB - 1) rowptr[M] = wb + s;   // total edge count
}

// --------------- pass 3: per-chunk exclusive scan + carry; heads MAY alias cnt
__global__ __launch_bounds__(256) void scan_final_kernel(const int* __restrict__ cnt,
                                                         const int* __restrict__ bbase,
                                                         int* __restrict__ rowptr,
                                                         int* __restrict__ heads, int M) {
    const int b = blockIdx.x;
    const int chunk = (M + SB - 1) / SB;
    const int lo = b * chunk;
    const int hi = min(M, lo + chunk);
    const int lane = threadIdx.x & 63;
    const int wv   = threadIdx.x >> 6;
    __shared__ int wsum[4];
    __shared__ int s_carry;
    if (threadIdx.x == 0) s_carry = bbase[b];
    __syncthreads();
    for (int base = lo; base < hi; base += 256) {
        const int i = base + (int)threadIdx.x;
        const int v = (i < hi) ? cnt[i] : 0;
        int s = v;
#pragma unroll
        for (int off = 1; off < 64; off <<= 1) {
            int t = __shfl_up(s, off);
            if (lane >= off) s += t;
        }
        if (lane == 63) wsum[wv] = s;
        __syncthreads();
        int wb = s_carry;
        for (int j = 0; j < wv; ++j) wb += wsum[j];
        const int excl = wb + s - v;
        if (i < hi) { rowptr[i] = excl; heads[i] = excl; }
        __syncthreads();
        if (threadIdx.x == 0) s_carry += wsum[0] + wsum[1] + wsum[2] + wsum[3];
        __syncthreads();
    }
}

// --------------------------------------- counting-sort edges by dest row
__global__ __launch_bounds__(256) void edge_sort_kernel(const int* __restrict__ erow,
                                                        const int* __restrict__ ecol,
                                                        const float* __restrict__ eval,
                                                        int* __restrict__ heads,
                                                        int* __restrict__ scol,
                                                        float* __restrict__ sval,
                                                        int nE) {
    int i = blockIdx.x * 256 + threadIdx.x;
    int stride = gridDim.x * 256;
    for (; i < nE; i += stride) {
        const int r = erow[i];
        const int p = atomicAdd(&heads[r], 1);
        scol[p] = ecol[i];
        sval[p] = eval[i];
    }
}

// ------------------------------------------- fused GEMM: Sup = bf16(X) * W
// BM=64 x BN=512 x BK=64, 512 threads (8 waves, each wave owns 64x64 output).
// A is reg-staged from fp32 X with in-register bf16 convert (cvt_x fused);
// B is global_load_lds from Wt. X is read exactly once (no N-tile re-reads).
// LDS 72 KB -> 2 blocks/CU.
__global__ __launch_bounds__(512, 4) void gemm_kernel(const float* __restrict__ X,
                                                      const unsigned short* __restrict__ Wt,
                                                      unsigned short* __restrict__ Sup,
                                                      int M) {
    __shared__ __align__(16) unsigned short As[BM * 64];    // 8 KB
    __shared__ __align__(16) unsigned short Bs[512 * 64];   // 64 KB
    const int tid  = threadIdx.x;
    const int wv   = tid >> 6;            // 0..7
    const int lane = tid & 63;
    const int tileM = blockIdx.x * BM;

    f32x4 acc[4][4];
#pragma unroll
    for (int i = 0; i < 4; ++i)
#pragma unroll
        for (int j = 0; j < 4; ++j) acc[i][j] = (f32x4)0.0f;

    const int srow = lane >> 3;               // row within 8-row chunk
    const int sgrn = (lane & 7) ^ srow;       // swizzled source granule
    const int scol = sgrn * 8;

    const int fm  = lane & 15;
    const int fkq = lane >> 4;                // 0..3

    // A source row for this thread's staging chunk (chunk c == wv)
    int arow = tileM + wv * 8 + srow;
    arow = (arow < M) ? arow : (M - 1);
    const float* agbase = X + (long)arow * D + scol;

    for (int kt = 0; kt < D; kt += 64) {
        __syncthreads();
        // ---- stage A: 8 fp32 -> 8 bf16 -> one ds_write_b128
        {
            const float* gx = agbase + kt;
            const float4 a = *(const float4*)gx;
            const float4 b = *(const float4*)(gx + 4);
            uint4 o;
            o.x = pack2(a.x, a.y);
            o.y = pack2(a.z, a.w);
            o.z = pack2(b.x, b.y);
            o.w = pack2(b.z, b.w);
            *(uint4*)(As + wv * 512 + lane * 8) = o;
        }
        // ---- stage B: 8 chunks per wave via global_load_lds
#pragma unroll
        for (int i = 0; i < 8; ++i) {
            const int c   = wv * 8 + i;           // 0..63
            const int row = c * 8 + srow;         // Wt row (n), 0..511
            const unsigned short* gb = Wt + (long)row * D + kt + scol;
            __builtin_amdgcn_global_load_lds(
                (const __attribute__((address_space(1))) void*)gb,
                (__attribute__((address_space(3))) void*)(Bs + c * 512), 16, 0, 0);
        }
        __syncthreads();
#pragma unroll
        for (int kk = 0; kk < 2; ++kk) {
            bf16x8 af[4], bfr[4];
#pragma unroll
            for (int mi = 0; mi < 4; ++mi) {
                const int m = mi * 16 + fm;
                const int g = (kk * 4 + fkq) ^ (m & 7);
                af[mi] = *(const bf16x8*)(As + m * 64 + g * 8);
            }
#pragma unroll
            for (int ni = 0; ni < 4; ++ni) {
                const int n = wv * 64 + ni * 16 + fm;
                const int g = (kk * 4 + fkq) ^ (n & 7);
                bfr[ni] = *(const bf16x8*)(Bs + n * 64 + g * 8);
            }
#pragma unroll
            for (int mi = 0; mi < 4; ++mi)
#pragma unroll
                for (int ni = 0; ni < 4; ++ni)
                    acc[mi][ni] = __builtin_amdgcn_mfma_f32_16x16x32_bf16(
                        af[mi], bfr[ni], acc[mi][ni], 0, 0, 0);
        }
    }

    const int colb = wv * 64 + fm;
#pragma unroll
    for (int mi = 0; mi < 4; ++mi) {
        const int rb = tileM + mi * 16 + fkq * 4;
#pragma unroll
        for (int r = 0; r < 4; ++r) {
            const int row = rb + r;
            if (row < M) {
                unsigned short* dst = Sup + (long)row * D + colb;
#pragma unroll
                for (int ni = 0; ni < 4; ++ni)
                    dst[ni * 16] = f2bf(acc[mi][ni][r]);
            }
        }
    }
}

// ----------------------------- pull aggregation, column-chunked:
// out[r][c0:c0+CHUNK] = b[c0:...] + sum val*Sup[col][c0:...]
// One wave per row; lane covers 4 cols (8B gathers). Two sequential launches.
__global__ __launch_bounds__(256) void aggregate_kernel(const unsigned short* __restrict__ sup,
                                                        const int* __restrict__ rowptr,
                                                        const int* __restrict__ scol,
                                                        const float* __restrict__ sval,
                                                        const float* __restrict__ bias,
                                                        float* __restrict__ out,
                                                        int M, int c0) {
    const int lane = threadIdx.x & 63;
    const int row  = (int)((blockIdx.x * 256 + threadIdx.x) >> 6);
    if (row >= M) return;
    int e = rowptr[row];
    const int end = rowptr[row + 1];

    const float4 b0 = *(const float4*)(bias + c0 + lane * 4);
    float acc[4] = {b0.x, b0.y, b0.z, b0.w};

    const unsigned short* supc = sup + c0 + lane * 4;   // per-lane column base

    for (; e + 4 <= end; e += 4) {
        const int cc0 = scol[e + 0], cc1 = scol[e + 1];
        const int cc2 = scol[e + 2], cc3 = scol[e + 3];
        const float v0 = sval[e + 0], v1 = sval[e + 1];
        const float v2 = sval[e + 2], v3 = sval[e + 3];
        const uint2 p0 = *(const uint2*)(supc + (long)cc0 * D);
        const uint2 p1 = *(const uint2*)(supc + (long)cc1 * D);
        const uint2 p2 = *(const uint2*)(supc + (long)cc2 * D);
        const uint2 p3 = *(const uint2*)(supc + (long)cc3 * D);
        acc[0] += v0 * bflo(p0.x); acc[1] += v0 * bfhi(p0.x);
        acc[2] += v0 * bflo(p0.y); acc[3] += v0 * bfhi(p0.y);
        acc[0] += v1 * bflo(p1.x); acc[1] += v1 * bfhi(p1.x);
        acc[2] += v1 * bflo(p1.y); acc[3] += v1 * bfhi(p1.y);
        acc[0] += v2 * bflo(p2.x); acc[1] += v2 * bfhi(p2.x);
        acc[2] += v2 * bflo(p2.y); acc[3] += v2 * bfhi(p2.y);
        acc[0] += v3 * bflo(p3.x); acc[1] += v3 * bfhi(p3.x);
        acc[2] += v3 * bflo(p3.y); acc[3] += v3 * bfhi(p3.y);
    }
    for (; e + 2 <= end; e += 2) {
        const int cc0 = scol[e + 0], cc1 = scol[e + 1];
        const float v0 = sval[e + 0], v1 = sval[e + 1];
        const uint2 p0 = *(const uint2*)(supc + (long)cc0 * D);
        const uint2 p1 = *(const uint2*)(supc + (long)cc1 * D);
        acc[0] += v0 * bflo(p0.x); acc[1] += v0 * bfhi(p0.x);
        acc[2] += v0 * bflo(p0.y); acc[3] += v0 * bfhi(p0.y);
        acc[0] += v1 * bflo(p1.x); acc[1] += v1 * bfhi(p1.x);
        acc[2] += v1 * bflo(p1.y); acc[3] += v1 * bfhi(p1.y);
    }
    for (; e < end; ++e) {
        const int cc = scol[e];
        const float v = sval[e];
        const uint2 p = *(const uint2*)(supc + (long)cc * D);
        acc[0] += v * bflo(p.x); acc[1] += v * bfhi(p.x);
        acc[2] += v * bflo(p.y); acc[3] += v * bfhi(p.y);
    }

    *(float4*)(out + (long)row * D + c0 + lane * 4) =
        (float4){acc[0], acc[1], acc[2], acc[3]};
}

extern "C" void kernel_launch(void* const* d_in, const int* in_sizes, int n_in,
                              void* d_out, int out_size, void* d_ws, size_t ws_size,
                              hipStream_t stream) {
    const float* x        = (const float*)d_in[0];
    const int*   adj_row  = (const int*)d_in[1];
    const int*   adj_col  = (const int*)d_in[2];
    const float* adj_vals = (const float*)d_in[3];
    const float* weight   = (const float*)d_in[4];
    const float* bias     = (const float*)d_in[5];
    float* out = (float*)d_out;

    const int M = in_sizes[0] / D;     // 100000 nodes
    const int E = in_sizes[1];         // 800000 edges

    // workspace layout (~110 MB)
    char* ws = (char*)d_ws;
    size_t off = 0;
    unsigned short* Sup = (unsigned short*)(ws + off); off += (size_t)M * D * 2;
    unsigned short* Wt  = (unsigned short*)(ws + off); off += (size_t)D * D * 2;
    int*   rowptr = (int*)(ws + off);   off += (size_t)(M + 1) * 4;
    int*   heads  = (int*)(ws + off);   off += (size_t)M * 4;        // also the histogram
    int*   scol   = (int*)(ws + off);   off += (size_t)E * 4;
    float* sval   = (float*)(ws + off); off += (size_t)E * 4;
    int*   bsum   = (int*)(ws + off);   off += (size_t)SB * 4;
    int*   bbase  = (int*)(ws + off);   off += (size_t)SB * 4;
    int* cnt = heads;                   // histogram aliases heads

    // --- CSR construction (independent of GEMM chain) ---
    zero_kernel<<<(M + 255) / 256, 256, 0, stream>>>(cnt, M);
    hist_kernel<<<1024, 256, 0, stream>>>(adj_row, cnt, E);
    scan_part_kernel<<<SB, 256, 0, stream>>>(cnt, bsum, M);
    scan_base_kernel<<<1, SB, 0, stream>>>(bsum, bbase, rowptr, M);
    scan_final_kernel<<<SB, 256, 0, stream>>>(cnt, bbase, rowptr, heads, M);
    edge_sort_kernel<<<1024, 256, 0, stream>>>(adj_row, adj_col, adj_vals,
                                               heads, scol, sval, E);

    // --- dense chain: fused cvt+GEMM ---
    cvt_w_kernel<<<dim3(D / 32, D / 32), 256, 0, stream>>>(weight, Wt);
    gemm_kernel<<<(M + BM - 1) / BM, 512, 0, stream>>>(x, Wt, Sup, M);

    // --- pull aggregation, 2 temporally-separated column passes ---
    aggregate_kernel<<<(M * 64 + 255) / 256, 256, 0, stream>>>(
        Sup, rowptr, scol, sval, bias, out, M, 0);
    aggregate_kernel<<<(M * 64 + 255) / 256, 256, 0, stream>>>(
        Sup, rowptr, scol, sval, bias, out, M, CHUNK);
}